// Round 1
// baseline (375.587 us; speedup 1.0000x reference)
//
#include <hip/hip_runtime.h>
#include <hip/hip_bf16.h>

// ---- constants for this problem ----
#define BB 4
#define TT 2048
#define C_IN 1152
#define NE 1024
#define NH 16
#define HD 64
#define MM (BB*TT)          // 8192
#define N_QKV (3*NE)        // 3072

typedef __attribute__((ext_vector_type(8))) short s16x8;
typedef __attribute__((ext_vector_type(4))) float f32x4;

static __device__ __forceinline__ unsigned short f2bf(float x) {
    unsigned int u = __float_as_uint(x);
    unsigned int r = (u + 0x7fffu + ((u >> 16) & 1u)) >> 16;
    return (unsigned short)r;
}

// async global->LDS, 16 B per lane. LDS dest = wave-uniform base + lane*16.
static __device__ __forceinline__ void async16(const void* g, void* l) {
    __builtin_amdgcn_global_load_lds((const __attribute__((address_space(1))) void*)g,
                                     (__attribute__((address_space(3))) void*)l, 16, 0, 0);
}

// ---------------- LayerNorm: x fp32 [M][C_IN] -> h bf16 [M][C_IN] ----------------
__global__ __launch_bounds__(256) void ln_kernel(const float* __restrict__ x,
                                                 const float* __restrict__ w,
                                                 const float* __restrict__ b,
                                                 unsigned short* __restrict__ h) {
    const int row = blockIdx.x;
    const float* xr = x + (size_t)row * C_IN;
    float s = 0.f, sq = 0.f;
    for (int i = threadIdx.x; i < C_IN; i += 256) {
        float v = xr[i];
        s += v; sq += v * v;
    }
    for (int off = 1; off < 64; off <<= 1) {
        s  += __shfl_xor(s, off, 64);
        sq += __shfl_xor(sq, off, 64);
    }
    __shared__ float red[2][4];
    const int wid = threadIdx.x >> 6, lane = threadIdx.x & 63;
    if (lane == 0) { red[0][wid] = s; red[1][wid] = sq; }
    __syncthreads();
    s  = red[0][0] + red[0][1] + red[0][2] + red[0][3];
    sq = red[1][0] + red[1][1] + red[1][2] + red[1][3];
    const float mu  = s * (1.f / C_IN);
    const float var = sq * (1.f / C_IN) - mu * mu;
    const float rs  = rsqrtf(var + 1e-5f);
    unsigned short* hr = h + (size_t)row * C_IN;
    for (int i = threadIdx.x; i < C_IN; i += 256) {
        float v = (xr[i] - mu) * rs * w[i] + b[i];
        hr[i] = f2bf(v);
    }
}

// ------------- transpose+cast: in fp32 [K][N] -> out bf16 [N][K] -------------
__global__ __launch_bounds__(256) void transpose_cast(const float* __restrict__ in,
                                                      unsigned short* __restrict__ out,
                                                      int K, int N) {
    __shared__ float tile[32][33];
    const int n0 = blockIdx.x * 32, k0 = blockIdx.y * 32;
    const int tx = threadIdx.x & 31, ty = threadIdx.x >> 5;   // 32 x 8
    for (int i = ty; i < 32; i += 8)
        tile[i][tx] = in[(size_t)(k0 + i) * N + n0 + tx];
    __syncthreads();
    for (int i = ty; i < 32; i += 8)
        out[(size_t)(n0 + i) * K + k0 + tx] = f2bf(tile[tx][i]);
}

#define ATT_SC 0.18033688011112042f   /* (1/8) * log2(e) */

// =====================================================================
// gemm_fm: 256x256 tile, BK=32, 512 threads (8 waves, 2M x 4N), MFMA 16x16x32.
//
// T2: LDS staged FRAGMENT-MAJOR via per-lane pre-permuted global source
//     (global_load_lds dest is linear: wave base + lane*16). Every ds_read_b128
//     is base + lane*16 -> contiguous 1 KiB, zero bank conflicts.
// T3+T4: 4 LDS buffers (128 KiB), prefetch distance 2 K-tiles; per-tile wait is
//     a COUNTED "s_waitcnt vmcnt(4)" (never 0 until the last tile). 2 phases/tile
//     (mf 0..3, mf 4..7), 16 independent MFMAs per phase, 2 barriers/tile.
// T5: s_setprio(1) around each MFMA cluster.
//
// MODE 0: qkv epilogue -> q (pre-scaled ATT_SC) / k in [bh][t][64] bf16,
//         v transposed [bh][64][t] bf16, all via LDS-routed 16B stores.
// MODE 1: fp32 out [M][N] direct stores.
// =====================================================================
#define EPAD 264   /* epilogue LDS row stride in shorts: 528 B, 16B-aligned */

template <int MODE>
__global__ __launch_bounds__(512, 2) void gemm_fm(const unsigned short* __restrict__ A,
                                                  const unsigned short* __restrict__ Bt,
                                                  const float* __restrict__ bias,
                                                  void* __restrict__ outp,
                                                  unsigned short* __restrict__ kb,
                                                  unsigned short* __restrict__ vt,
                                                  int M, int N, int K) {
    __shared__ unsigned short sm[65536];        // 128 KiB: A bufs [4][8192] | B bufs [4][8192]
    unsigned short* sA = sm;
    unsigned short* sB = sm + 32768;
    const int tid = threadIdx.x;
    const int lane = tid & 63, wid = tid >> 6;
    const int wm = wid >> 2, wn = wid & 3;      // 2 x 4 wave grid; wave owns 128m x 64n
    const int quad = lane >> 4, l16 = lane & 15;
    const int m0 = blockIdx.y * 256, n0 = blockIdx.x * 256;

    // staging source: lane covers fragment-row fr = l16, k-chunk fc = quad.
    // load j=0 -> blocks 0..7 (b = wid, rows m0 + b*16), j=1 -> blocks 8..15.
    const unsigned short* gA0 = A  + (size_t)(m0 + wid * 16 + l16) * K + quad * 8;
    const unsigned short* gB0 = Bt + (size_t)(n0 + wid * 16 + l16) * K + quad * 8;
    const size_t j1 = (size_t)128 * K;
    // wave-uniform LDS short offsets (HW appends lane*16B = 8 shorts)
    const int stA0 = wid * 512, stA1 = (8 + wid) * 512;

    f32x4 acc[8][4] = {};
    const int nk = K >> 5;

    // ---- prologue: stage tiles 0 and 1 (4 loads each: A j0,j1 + B j0,j1) ----
    async16(gA0,           &sA[stA0]);          async16(gA0 + j1,      &sA[stA1]);
    async16(gB0,           &sB[stA0]);          async16(gB0 + j1,      &sB[stA1]);
    async16(gA0 + 32,      &sA[8192 + stA0]);   async16(gA0 + j1 + 32, &sA[8192 + stA1]);
    async16(gB0 + 32,      &sB[8192 + stA0]);   async16(gB0 + j1 + 32, &sB[8192 + stA1]);

    for (int kt = 0; kt < nk; ++kt) {
        const int cb = (kt & 3) * 8192;
        // counted wait: tile kt's 4 loads done; tile kt+1's 4 remain in flight.
        if (kt + 1 < nk) { asm volatile("s_waitcnt vmcnt(4)" ::: "memory"); }
        else             { asm volatile("s_waitcnt vmcnt(0)" ::: "memory"); }
        __builtin_amdgcn_s_barrier();

        const int pre = kt + 2;
        const bool do_pre = (pre < nk);
        const int pb = (pre & 3) * 8192;
        const unsigned short* pA = gA0 + pre * 32;
        const unsigned short* pB = gB0 + pre * 32;

        s16x8 af[4], bf[4];
        // ---- phase 0: A frags (wm half 0) + all B frags; stage A of tile kt+2 ----
        #pragma unroll
        for (int i = 0; i < 4; i++)
            af[i] = *(const s16x8*)&sA[cb + (wm * 8 + i) * 512 + lane * 8];
        #pragma unroll
        for (int i = 0; i < 4; i++)
            bf[i] = *(const s16x8*)&sB[cb + (wn * 4 + i) * 512 + lane * 8];
        if (do_pre) { async16(pA, &sA[pb + stA0]); async16(pA + j1, &sA[pb + stA1]); }
        __builtin_amdgcn_s_setprio(1);
        #pragma unroll
        for (int mi = 0; mi < 4; mi++)
            #pragma unroll
            for (int ni = 0; ni < 4; ni++)
                acc[mi][ni] = __builtin_amdgcn_mfma_f32_16x16x32_bf16(af[mi], bf[ni], acc[mi][ni], 0, 0, 0);
        __builtin_amdgcn_s_setprio(0);
        __builtin_amdgcn_s_barrier();

        // ---- phase 1: A frags (wm half 1), reuse B regs; stage B of tile kt+2 ----
        #pragma unroll
        for (int i = 0; i < 4; i++)
            af[i] = *(const s16x8*)&sA[cb + (wm * 8 + 4 + i) * 512 + lane * 8];
        if (do_pre) { async16(pB, &sB[pb + stA0]); async16(pB + j1, &sB[pb + stA1]); }
        __builtin_amdgcn_s_setprio(1);
        #pragma unroll
        for (int mi = 0; mi < 4; mi++)
            #pragma unroll
            for (int ni = 0; ni < 4; ni++)
                acc[4 + mi][ni] = __builtin_amdgcn_mfma_f32_16x16x32_bf16(af[mi], bf[ni], acc[4 + mi][ni], 0, 0, 0);
        __builtin_amdgcn_s_setprio(0);
        // tile-end barrier = next iteration's top barrier
    }

    // ---- bias into registers ----
    float bv[4];
    #pragma unroll
    for (int ni = 0; ni < 4; ni++)
        bv[ni] = bias[n0 + wn * 64 + ni * 16 + l16];

    if (MODE == 1) {
        float* out = (float*)outp;
        #pragma unroll
        for (int mf = 0; mf < 8; mf++) {
            const int mg = m0 + wm * 128 + mf * 16 + quad * 4;
            #pragma unroll
            for (int ni = 0; ni < 4; ni++) {
                const int ng = n0 + wn * 64 + ni * 16 + l16;
                #pragma unroll
                for (int r = 0; r < 4; r++)
                    out[(size_t)(mg + r) * N + ng] = acc[mf][ni][r] + bv[ni];
            }
        }
        return;
    }

    // ---- MODE 0: LDS-routed coalesced epilogue ----
    const int which = n0 >> 10;                 // 0=q 1=k 2=v (uniform; 256-tile never straddles)
    const int bb = m0 >> 11;
    const int mloc = m0 & 2047;
    const float sc = (which == 0) ? ATT_SC : 1.0f;
    unsigned short* T = sm;                     // reuse LDS: [64][EPAD]

    if (which < 2) {
        // row layout [t][d]; 4 passes over 64-row m-chunks
        unsigned short* qk = (which == 0) ? (unsigned short*)outp : kb;
        const int hb = (n0 & 1023) >> 6;
        for (int p = 0; p < 4; p++) {
            __syncthreads();
            if (wm == (p >> 1)) {
                #pragma unroll
                for (int i = 0; i < 4; i++) {
                    const int mf = (p & 1) * 4 + i;
                    #pragma unroll
                    for (int ni = 0; ni < 4; ni++) {
                        const int col = wn * 64 + ni * 16 + l16;
                        #pragma unroll
                        for (int r = 0; r < 4; r++)
                            T[(i * 16 + quad * 4 + r) * EPAD + col] =
                                f2bf((acc[mf][ni][r] + bv[ni]) * sc);
                    }
                }
            }
            __syncthreads();
            const int c0 = (tid & 31) * 8;
            const int hh = hb + (c0 >> 6), d0 = c0 & 63;
            for (int rr = tid >> 5; rr < 64; rr += 16) {
                const int t = mloc + p * 64 + rr;
                *(s16x8*)(qk + ((size_t)(bb * 16 + hh) * TT + t) * HD + d0) =
                    *(const s16x8*)&T[rr * EPAD + c0];
            }
        }
    } else {
        // transposed layout [d][t]; 4 passes over 64-col n-chunks (one head each)
        const int hb = (n0 - 2048) >> 6;
        for (int p = 0; p < 4; p++) {
            __syncthreads();
            if (wn == p) {
                #pragma unroll
                for (int mf = 0; mf < 8; mf++) {
                    const int colb = wm * 128 + mf * 16 + quad * 4;
                    #pragma unroll
                    for (int ni = 0; ni < 4; ni++) {
                        const int rowt = ni * 16 + l16;
                        const unsigned int pk0 =
                            (unsigned int)f2bf(acc[mf][ni][0] + bv[ni]) |
                            ((unsigned int)f2bf(acc[mf][ni][1] + bv[ni]) << 16);
                        const unsigned int pk1 =
                            (unsigned int)f2bf(acc[mf][ni][2] + bv[ni]) |
                            ((unsigned int)f2bf(acc[mf][ni][3] + bv[ni]) << 16);
                        *(unsigned int*)&T[rowt * EPAD + colb]     = pk0;
                        *(unsigned int*)&T[rowt * EPAD + colb + 2] = pk1;
                    }
                }
            }
            __syncthreads();
            const int c0 = (tid & 31) * 8;
            for (int dr = tid >> 5; dr < 64; dr += 16) {
                *(s16x8*)(vt + ((size_t)(bb * 16 + hb + p) * HD + dr) * TT + mloc + c0) =
                    *(const s16x8*)&T[dr * EPAD + c0];
            }
        }
    }
}

// ------------- flash attention: S^T trick + ones-MFMA row sums -------------
// q (pre-scaled by ATT_SC), k [BH][T][64] bf16, vt [BH][64][T] bf16 -> y bf16 [B][T][NE]
#define PST 72                         /* shorts; 144 B rows, 16B-aligned */

__global__ __launch_bounds__(256) void attn_kernel(const unsigned short* __restrict__ qb,
                                                   const unsigned short* __restrict__ kb,
                                                   const unsigned short* __restrict__ vt,
                                                   unsigned short* __restrict__ yb) {
    __shared__ unsigned short Ks[2][64 * 64];
    __shared__ unsigned short Vs[2][64 * 64];
    __shared__ unsigned short Ps[4][2 * 16 * PST];   // per-wave, per-mf [16 q][PST]
    const int tid = threadIdx.x, wid = tid >> 6, lane = tid & 63;
    const int quad = lane >> 4, l16 = lane & 15;
    const int bh = blockIdx.x & 63;
    const int qblk = 15 - (blockIdx.x >> 6);         // longest-first (LPT packing)

    const unsigned short* qh = qb + (size_t)bh * TT * HD;
    const unsigned short* kh = kb + (size_t)bh * TT * HD;
    const unsigned short* vh = vt + (size_t)bh * HD * TT;
    unsigned short* ps = Ps[wid];

    const int q0w = qblk * 128 + wid * 32;           // this wave's 32 q-rows
    s16x8 aq[2][2];
    #pragma unroll
    for (int mf = 0; mf < 2; mf++) {
        aq[mf][0] = *(const s16x8*)&qh[(size_t)(q0w + mf * 16 + l16) * HD + quad * 8];
        aq[mf][1] = *(const s16x8*)&qh[(size_t)(q0w + mf * 16 + l16) * HD + 32 + quad * 8];
    }
    // ones B-frag (bf16 1.0 = 0x3F80)
    s16x8 onesf;
    #pragma unroll
    for (int i = 0; i < 8; i++) onesf[i] = (short)0x3F80;

    f32x4 yacc[2][4] = {};
    f32x4 lacc[2] = {};                              // row-sum accumulators
    const int ntiles = 2 * qblk + 2;                 // always even

    // staging: row r = wid*16 + {0,8} + rl, chunk cc XOR-swizzled; pointers bumped
    const int rl = lane >> 3;
    const int cc = (lane & 7) ^ (rl & 7);
    const unsigned short* kp0 = kh + (size_t)(wid * 16 + rl) * HD + cc * 8;
    const unsigned short* kp1 = kh + (size_t)(wid * 16 + 8 + rl) * HD + cc * 8;
    const unsigned short* vp0 = vh + (size_t)(wid * 16 + rl) * TT + cc * 8;
    const unsigned short* vp1 = vh + (size_t)(wid * 16 + 8 + rl) * TT + cc * 8;
    const int ldsK0 = wid * 16 * 64, ldsK1 = (wid * 16 + 8) * 64;

    // prologue: stage tile 0 into buffer 0; bump to tile 1
    async16(kp0, &Ks[0][ldsK0]);  async16(kp1, &Ks[0][ldsK1]);
    async16(vp0, &Vs[0][ldsK0]);  async16(vp1, &Vs[0][ldsK1]);
    kp0 += 64 * HD; kp1 += 64 * HD; vp0 += 64; vp1 += 64;

    const int p0s = quad ^ (l16 & 7);
    const int p1s = (4 + quad) ^ (l16 & 7);

#define ATT_STEP(CUR, TT_)                                                              \
    {                                                                                   \
        __syncthreads();                                                                \
        if ((TT_) + 1 < ntiles) {                                                       \
            async16(kp0, &Ks[(CUR) ^ 1][ldsK0]);  async16(kp1, &Ks[(CUR) ^ 1][ldsK1]);  \
            async16(vp0, &Vs[(CUR) ^ 1][ldsK0]);  async16(vp1, &Vs[(CUR) ^ 1][ldsK1]);  \
            kp0 += 64 * HD; kp1 += 64 * HD; vp0 += 64; vp1 += 64;                       \
        }                                                                               \
        const int tk0 = (TT_) * 64;                                                     \
        if (tk0 <= q0w + 31) {                                                          \
            const unsigned short* Kc = Ks[CUR];                                         \
            const unsigned short* Vc = Vs[CUR];                                         \
            s16x8 kf[4][2], vf[4][2];                                                   \
            _Pragma("unroll")                                                           \
            for (int nj = 0; nj < 4; nj++) {                                            \
                kf[nj][0] = *(const s16x8*)&Kc[(nj * 16 + l16) * 64 + p0s * 8];         \
                kf[nj][1] = *(const s16x8*)&Kc[(nj * 16 + l16) * 64 + p1s * 8];         \
            }                                                                           \
            _Pragma("unroll")                                                           \
            for (int ni = 0; ni < 4; ni++) {                                            \
                vf[ni][0] = *(const s16x8*)&Vc[(ni * 16 + l16) * 64 + p0s * 8];         \
                vf[ni][1] = *(const s16x8*)&Vc[(ni * 16 + l16) * 64 + p1s * 8];         \
            }                                                                           \
            _Pragma("unroll")                                                           \
            for (int mf = 0; mf < 2; mf++) {                                            \
                const int f0 = q0w + mf * 16;                                           \
                if (tk0 > f0 + 15) continue;                                            \
                unsigned short* pm = ps + mf * (16 * PST);                              \
                const int qg = f0 + l16;                                                \
                f32x4 st[4];                                                            \
                _Pragma("unroll")                                                       \
                for (int nj = 0; nj < 4; nj++) {                                        \
                    f32x4 z = {};                                                       \
                    z = __builtin_amdgcn_mfma_f32_16x16x32_bf16(kf[nj][0], aq[mf][0], z, 0, 0, 0); \
                    z = __builtin_amdgcn_mfma_f32_16x16x32_bf16(kf[nj][1], aq[mf][1], z, 0, 0, 0); \
                    st[nj] = z;                                                         \
                }                                                                       \
                const bool diag = (tk0 + 64 > f0);                                      \
                _Pragma("unroll")                                                       \
                for (int nj = 0; nj < 4; nj++) {                                        \
                    const int keyb = tk0 + nj * 16 + quad * 4;                          \
                    float pv[4];                                                        \
                    _Pragma("unroll")                                                   \
                    for (int r = 0; r < 4; r++) {                                       \
                        float p = exp2f(st[nj][r]);                                     \
                        if (diag && (keyb + r > qg)) p = 0.f;                           \
                        pv[r] = p;                                                      \
                    }                                                                   \
                    const unsigned int pk0 = __builtin_amdgcn_perm(                     \
                        __float_as_uint(pv[1]), __float_as_uint(pv[0]), 0x07060302u);   \
                    const unsigned int pk1 = __builtin_amdgcn_perm(                     \
                        __float_as_uint(pv[3]), __float_as_uint(pv[2]), 0x07060302u);   \
                    *(uint2*)&pm[l16 * PST + nj * 16 + quad * 4] = make_uint2(pk0, pk1);\
                }                                                                       \
                __asm volatile("s_waitcnt lgkmcnt(0)" ::: "memory");                    \
                const s16x8 ap0 = *(const s16x8*)&pm[l16 * PST + quad * 8];             \
                const s16x8 ap1 = *(const s16x8*)&pm[l16 * PST + 32 + quad * 8];        \
                lacc[mf] = __builtin_amdgcn_mfma_f32_16x16x32_bf16(ap0, onesf, lacc[mf], 0, 0, 0); \
                lacc[mf] = __builtin_amdgcn_mfma_f32_16x16x32_bf16(ap1, onesf, lacc[mf], 0, 0, 0); \
                _Pragma("unroll")                                                       \
                for (int ni = 0; ni < 4; ni++) {                                        \
                    yacc[mf][ni] = __builtin_amdgcn_mfma_f32_16x16x32_bf16(ap0, vf[ni][0], yacc[mf][ni], 0, 0, 0); \
                    yacc[mf][ni] = __builtin_amdgcn_mfma_f32_16x16x32_bf16(ap1, vf[ni][1], yacc[mf][ni], 0, 0, 0); \
                }                                                                       \
            }                                                                           \
        }                                                                               \
    }

    for (int t = 0; t < ntiles; t += 2) {
        ATT_STEP(0, t);
        ATT_STEP(1, t + 1);
    }
#undef ATT_STEP

    // epilogue: lacc[mf][r] is the denominator for q = f0 + quad*4 + r
    const int bbi = bh >> 4, hh = bh & 15;
    #pragma unroll
    for (int mf = 0; mf < 2; mf++) {
        float linv[4];
        #pragma unroll
        for (int r = 0; r < 4; r++)
            linv[r] = 1.0f / lacc[mf][r];
        #pragma unroll
        for (int ni = 0; ni < 4; ni++)
            #pragma unroll
            for (int r = 0; r < 4; r++) {
                const int trow = q0w + mf * 16 + quad * 4 + r;
                yb[((size_t)bbi * TT + trow) * NE + hh * HD + ni * 16 + l16] =
                    f2bf(yacc[mf][ni][r] * linv[r]);
            }
    }
}

extern "C" void kernel_launch(void* const* d_in, const int* in_sizes, int n_in,
                              void* d_out, int out_size, void* d_ws, size_t ws_size,
                              hipStream_t stream) {
    const float* x      = (const float*)d_in[0];
    const float* ln_w   = (const float*)d_in[1];
    const float* ln_b   = (const float*)d_in[2];
    const float* W_attn = (const float*)d_in[3];
    const float* b_attn = (const float*)d_in[4];
    const float* W_proj = (const float*)d_in[5];
    const float* b_proj = (const float*)d_in[6];
    float* out = (float*)d_out;

    char* ws = (char*)d_ws;
    unsigned short* h    = (unsigned short*)ws;  ws += (size_t)MM * C_IN * 2;
    unsigned short* Wat  = (unsigned short*)ws;  ws += (size_t)N_QKV * C_IN * 2;
    unsigned short* Wpt  = (unsigned short*)ws;  ws += (size_t)NE * NE * 2;
    unsigned short* qbuf = (unsigned short*)ws;  ws += (size_t)MM * NE * 2;
    unsigned short* kbuf = (unsigned short*)ws;  ws += (size_t)MM * NE * 2;
    unsigned short* vtbf = (unsigned short*)ws;  ws += (size_t)MM * NE * 2;
    unsigned short* ybuf = (unsigned short*)ws;  ws += (size_t)MM * NE * 2;

    ln_kernel<<<MM, 256, 0, stream>>>(x, ln_w, ln_b, h);
    transpose_cast<<<dim3(N_QKV / 32, C_IN / 32), 256, 0, stream>>>(W_attn, Wat, C_IN, N_QKV);
    transpose_cast<<<dim3(NE / 32, NE / 32), 256, 0, stream>>>(W_proj, Wpt, NE, NE);
    gemm_fm<0><<<dim3(N_QKV / 256, MM / 256), 512, 0, stream>>>(h, Wat, b_attn, qbuf, kbuf, vtbf,
                                                                MM, N_QKV, C_IN);
    attn_kernel<<<64 * 16, 256, 0, stream>>>(qbuf, kbuf, vtbf, ybuf);
    gemm_fm<1><<<dim3(NE / 256, MM / 256), 512, 0, stream>>>(ybuf, Wpt, b_proj, out, nullptr, nullptr,
                                                             MM, NE, NE);
}

// Round 2
// 368.797 us; speedup vs baseline: 1.0184x; 1.0184x over previous
//
#include <hip/hip_runtime.h>
#include <hip/hip_bf16.h>

// ---- constants for this problem ----
#define BB 4
#define TT 2048
#define C_IN 1152
#define NE 1024
#define NH 16
#define HD 64
#define MM (BB*TT)          // 8192
#define N_QKV (3*NE)        // 3072

typedef __attribute__((ext_vector_type(8))) short s16x8;
typedef __attribute__((ext_vector_type(4))) float f32x4;

static __device__ __forceinline__ unsigned short f2bf(float x) {
    unsigned int u = __float_as_uint(x);
    unsigned int r = (u + 0x7fffu + ((u >> 16) & 1u)) >> 16;
    return (unsigned short)r;
}

// async global->LDS, 16 B per lane. LDS dest = wave-uniform base + lane*16.
static __device__ __forceinline__ void async16(const void* g, void* l) {
    __builtin_amdgcn_global_load_lds((const __attribute__((address_space(1))) void*)g,
                                     (__attribute__((address_space(3))) void*)l, 16, 0, 0);
}

// ---------------- LayerNorm: x fp32 [M][C_IN] -> h bf16 [M][C_IN] ----------------
__global__ __launch_bounds__(256) void ln_kernel(const float* __restrict__ x,
                                                 const float* __restrict__ w,
                                                 const float* __restrict__ b,
                                                 unsigned short* __restrict__ h) {
    const int row = blockIdx.x;
    const float* xr = x + (size_t)row * C_IN;
    float s = 0.f, sq = 0.f;
    for (int i = threadIdx.x; i < C_IN; i += 256) {
        float v = xr[i];
        s += v; sq += v * v;
    }
    for (int off = 1; off < 64; off <<= 1) {
        s  += __shfl_xor(s, off, 64);
        sq += __shfl_xor(sq, off, 64);
    }
    __shared__ float red[2][4];
    const int wid = threadIdx.x >> 6, lane = threadIdx.x & 63;
    if (lane == 0) { red[0][wid] = s; red[1][wid] = sq; }
    __syncthreads();
    s  = red[0][0] + red[0][1] + red[0][2] + red[0][3];
    sq = red[1][0] + red[1][1] + red[1][2] + red[1][3];
    const float mu  = s * (1.f / C_IN);
    const float var = sq * (1.f / C_IN) - mu * mu;
    const float rs  = rsqrtf(var + 1e-5f);
    unsigned short* hr = h + (size_t)row * C_IN;
    for (int i = threadIdx.x; i < C_IN; i += 256) {
        float v = (xr[i] - mu) * rs * w[i] + b[i];
        hr[i] = f2bf(v);
    }
}

// ------------- transpose+cast: in fp32 [K][N] -> out bf16 [N][K] -------------
__global__ __launch_bounds__(256) void transpose_cast(const float* __restrict__ in,
                                                      unsigned short* __restrict__ out,
                                                      int K, int N) {
    __shared__ float tile[32][33];
    const int n0 = blockIdx.x * 32, k0 = blockIdx.y * 32;
    const int tx = threadIdx.x & 31, ty = threadIdx.x >> 5;   // 32 x 8
    for (int i = ty; i < 32; i += 8)
        tile[i][tx] = in[(size_t)(k0 + i) * N + n0 + tx];
    __syncthreads();
    for (int i = ty; i < 32; i += 8)
        out[(size_t)(n0 + i) * K + k0 + tx] = f2bf(tile[tx][i]);
}

#define ATT_SC 0.18033688011112042f   /* (1/8) * log2(e) */

// =====================================================================
// gemm_fm: BM=256 x BN=(256|128) tile, BK=32, 512 threads (8 waves, 2M x 4N).
//
// - Fragment-major LDS (zero bank conflicts): one async16 instruction stages
//   exactly one 16x32 MFMA fragment (64 lanes x 16 B), per-lane pre-permuted
//   global source, linear LDS dest. Every ds_read_b128 = base + lane*16.
// - 4 K-tile buffers, prefetch distance 3, counted vmcnt (2R steady, R, 0 at
//   the tail). ONE barrier + ONE wait per K-tile; no mid-tile barrier.
// - T1: bijective XCD-chunked blockIdx swizzle (nwg % 8 == 0 for both grids).
// - T5: setprio(1) around the 32-MFMA cluster.
//
// MODE 0: BN=256; qkv epilogue -> q (pre-scaled ATT_SC) / k in [bh][t][64],
//         v transposed [bh][64][t], all bf16 via LDS-routed 16B stores.
// MODE 1: BN=128; fp32 out [M][N] direct stores. Grid (8,32)=256 blocks.
// =====================================================================
#define EPAD 264   /* epilogue LDS row stride in shorts: 528 B, 16B-aligned */

template <int MODE>
__global__ __launch_bounds__(512, 2) void gemm_fm(const unsigned short* __restrict__ A,
                                                  const unsigned short* __restrict__ Bt,
                                                  const float* __restrict__ bias,
                                                  void* __restrict__ outp,
                                                  unsigned short* __restrict__ kb,
                                                  unsigned short* __restrict__ vt,
                                                  int M, int N, int K) {
    constexpr int BN      = (MODE == 0) ? 256 : 128;
    constexpr int NB      = BN / 64;        // n-frags per wave: 4 or 2
    constexpr int BROUNDS = BN / 128;       // staging rounds for B: 2 or 1
    constexpr int ABUF    = 8192;           // shorts per A k-tile buffer (16 KB)
    constexpr int BBUF    = BROUNDS * 4096; // shorts per B k-tile buffer

    __shared__ unsigned short sm[4 * (ABUF + BBUF)];
    unsigned short* sA = sm;
    unsigned short* sB = sm + 4 * ABUF;

    const int tid = threadIdx.x;
    const int lane = tid & 63, wid = tid >> 6;
    const int wm = wid >> 2, wn = wid & 3;      // wave owns 128m x (BN/4)n
    const int quad = lane >> 4, l16 = lane & 15;

    // ---- T1: bijective XCD-chunked swizzle ----
    const int gx  = gridDim.x;
    const int nwg = gx * gridDim.y;
    const int bid = blockIdx.y * gx + blockIdx.x;
    const int wg  = (bid & 7) * (nwg >> 3) + (bid >> 3);
    const int m0  = (wg / gx) * 256;
    const int n0  = (wg % gx) * BN;

    // staging source: fragment f covers rows f*16 + l16, cols quad*8 (+kt*32)
    const unsigned short* gA = A  + (size_t)(m0 + wid * 16 + l16) * K + quad * 8;
    const unsigned short* gB = Bt + (size_t)(n0 + wid * 16 + l16) * K + quad * 8;
    const size_t jA = (size_t)128 * K;          // +8 fragments (128 rows)

    f32x4 acc[8][NB] = {};
    const int nk = K >> 5;

    auto STAGE = [&](int t) {
        const int b = t & 3;
        const unsigned short* pa = gA + (size_t)t * 32;
        const unsigned short* pb = gB + (size_t)t * 32;
        async16(pa,      &sA[b * ABUF + wid * 512]);
        async16(pa + jA, &sA[b * ABUF + (8 + wid) * 512]);
        async16(pb,      &sB[b * BBUF + wid * 512]);
        if (BROUNDS == 2)
            async16(pb + jA, &sB[b * BBUF + (8 + wid) * 512]);
    };

    // prologue: stage tiles 0..2
    STAGE(0);
    if (nk > 1) STAGE(1);
    if (nk > 2) STAGE(2);

    for (int kt = 0; kt < nk; ++kt) {
        // counted wait: tile kt's R loads done; up to 2R newer stay in flight
        if (kt + 2 < nk) {
            if (MODE == 0) asm volatile("s_waitcnt vmcnt(8)" ::: "memory");
            else           asm volatile("s_waitcnt vmcnt(6)" ::: "memory");
        } else if (kt + 1 < nk) {
            if (MODE == 0) asm volatile("s_waitcnt vmcnt(4)" ::: "memory");
            else           asm volatile("s_waitcnt vmcnt(3)" ::: "memory");
        } else {
            asm volatile("s_waitcnt vmcnt(0)" ::: "memory");
        }
        __builtin_amdgcn_s_barrier();
        if (kt + 3 < nk) STAGE(kt + 3);     // overwrites buffer read at kt-1

        const int cb  = (kt & 3) * ABUF;
        const int cbB = (kt & 3) * BBUF;
        s16x8 af[8], bf[NB];
        #pragma unroll
        for (int mf = 0; mf < 8; mf++)
            af[mf] = *(const s16x8*)&sA[cb + (wm * 8 + mf) * 512 + lane * 8];
        #pragma unroll
        for (int ni = 0; ni < NB; ni++)
            bf[ni] = *(const s16x8*)&sB[cbB + (wn * NB + ni) * 512 + lane * 8];
        __builtin_amdgcn_s_setprio(1);
        #pragma unroll
        for (int mf = 0; mf < 8; mf++)
            #pragma unroll
            for (int ni = 0; ni < NB; ni++)
                acc[mf][ni] = __builtin_amdgcn_mfma_f32_16x16x32_bf16(af[mf], bf[ni], acc[mf][ni], 0, 0, 0);
        __builtin_amdgcn_s_setprio(0);
    }

    // ---- bias into registers ----
    float bv[NB];
    #pragma unroll
    for (int ni = 0; ni < NB; ni++)
        bv[ni] = bias[n0 + wn * (BN / 4) + ni * 16 + l16];

    if (MODE == 1) {
        float* out = (float*)outp;
        #pragma unroll
        for (int mf = 0; mf < 8; mf++) {
            const int mg = m0 + wm * 128 + mf * 16 + quad * 4;
            #pragma unroll
            for (int ni = 0; ni < NB; ni++) {
                const int ng = n0 + wn * (BN / 4) + ni * 16 + l16;
                #pragma unroll
                for (int r = 0; r < 4; r++)
                    out[(size_t)(mg + r) * N + ng] = acc[mf][ni][r] + bv[ni];
            }
        }
        return;
    }

    // ---- MODE 0: LDS-routed coalesced epilogue ----
    const int which = n0 >> 10;                 // 0=q 1=k 2=v (uniform)
    const int bb = m0 >> 11;
    const int mloc = m0 & 2047;
    const float sc = (which == 0) ? ATT_SC : 1.0f;
    unsigned short* T = sm;                     // reuse LDS: [64][EPAD]

    if (which < 2) {
        // row layout [t][d]; 4 passes over 64-row m-chunks
        unsigned short* qk = (which == 0) ? (unsigned short*)outp : kb;
        const int hb = (n0 & 1023) >> 6;
        for (int p = 0; p < 4; p++) {
            __syncthreads();
            if (wm == (p >> 1)) {
                #pragma unroll
                for (int i = 0; i < 4; i++) {
                    const int mf = (p & 1) * 4 + i;
                    #pragma unroll
                    for (int ni = 0; ni < 4; ni++) {
                        const int col = wn * 64 + ni * 16 + l16;
                        #pragma unroll
                        for (int r = 0; r < 4; r++)
                            T[(i * 16 + quad * 4 + r) * EPAD + col] =
                                f2bf((acc[mf][ni][r] + bv[ni]) * sc);
                    }
                }
            }
            __syncthreads();
            const int c0 = (tid & 31) * 8;
            const int hh = hb + (c0 >> 6), d0 = c0 & 63;
            for (int rr = tid >> 5; rr < 64; rr += 16) {
                const int t = mloc + p * 64 + rr;
                *(s16x8*)(qk + ((size_t)(bb * 16 + hh) * TT + t) * HD + d0) =
                    *(const s16x8*)&T[rr * EPAD + c0];
            }
        }
    } else {
        // transposed layout [d][t]; 4 passes over 64-col n-chunks (one head each)
        const int hb = (n0 - 2048) >> 6;
        for (int p = 0; p < 4; p++) {
            __syncthreads();
            if (wn == p) {
                #pragma unroll
                for (int mf = 0; mf < 8; mf++) {
                    const int colb = wm * 128 + mf * 16 + quad * 4;
                    #pragma unroll
                    for (int ni = 0; ni < 4; ni++) {
                        const int rowt = ni * 16 + l16;
                        const unsigned int pk0 =
                            (unsigned int)f2bf(acc[mf][ni][0] + bv[ni]) |
                            ((unsigned int)f2bf(acc[mf][ni][1] + bv[ni]) << 16);
                        const unsigned int pk1 =
                            (unsigned int)f2bf(acc[mf][ni][2] + bv[ni]) |
                            ((unsigned int)f2bf(acc[mf][ni][3] + bv[ni]) << 16);
                        *(unsigned int*)&T[rowt * EPAD + colb]     = pk0;
                        *(unsigned int*)&T[rowt * EPAD + colb + 2] = pk1;
                    }
                }
            }
            __syncthreads();
            const int c0 = (tid & 31) * 8;
            for (int dr = tid >> 5; dr < 64; dr += 16) {
                *(s16x8*)(vt + ((size_t)(bb * 16 + hb + p) * HD + dr) * TT + mloc + c0) =
                    *(const s16x8*)&T[dr * EPAD + c0];
            }
        }
    }
}

// ------------- flash attention: S^T trick + ones-MFMA row sums -------------
// q (pre-scaled by ATT_SC), k [BH][T][64] bf16, vt [BH][64][T] bf16 -> y bf16 [B][T][NE]
#define PST 72                         /* shorts; 144 B rows, 16B-aligned */

__global__ __launch_bounds__(256) void attn_kernel(const unsigned short* __restrict__ qb,
                                                   const unsigned short* __restrict__ kb,
                                                   const unsigned short* __restrict__ vt,
                                                   unsigned short* __restrict__ yb) {
    __shared__ unsigned short Ks[2][64 * 64];
    __shared__ unsigned short Vs[2][64 * 64];
    __shared__ unsigned short Ps[4][2 * 16 * PST];   // per-wave, per-mf [16 q][PST]
    const int tid = threadIdx.x, wid = tid >> 6, lane = tid & 63;
    const int quad = lane >> 4, l16 = lane & 15;
    const int bh = blockIdx.x & 63;
    const int qblk = 15 - (blockIdx.x >> 6);         // longest-first (LPT packing)

    const unsigned short* qh = qb + (size_t)bh * TT * HD;
    const unsigned short* kh = kb + (size_t)bh * TT * HD;
    const unsigned short* vh = vt + (size_t)bh * HD * TT;
    unsigned short* ps = Ps[wid];

    const int q0w = qblk * 128 + wid * 32;           // this wave's 32 q-rows
    s16x8 aq[2][2];
    #pragma unroll
    for (int mf = 0; mf < 2; mf++) {
        aq[mf][0] = *(const s16x8*)&qh[(size_t)(q0w + mf * 16 + l16) * HD + quad * 8];
        aq[mf][1] = *(const s16x8*)&qh[(size_t)(q0w + mf * 16 + l16) * HD + 32 + quad * 8];
    }
    // ones B-frag (bf16 1.0 = 0x3F80)
    s16x8 onesf;
    #pragma unroll
    for (int i = 0; i < 8; i++) onesf[i] = (short)0x3F80;

    f32x4 yacc[2][4] = {};
    f32x4 lacc[2] = {};                              // row-sum accumulators
    const int ntiles = 2 * qblk + 2;                 // always even

    // staging: row r = wid*16 + {0,8} + rl, chunk cc XOR-swizzled; pointers bumped
    const int rl = lane >> 3;
    const int cc = (lane & 7) ^ (rl & 7);
    const unsigned short* kp0 = kh + (size_t)(wid * 16 + rl) * HD + cc * 8;
    const unsigned short* kp1 = kh + (size_t)(wid * 16 + 8 + rl) * HD + cc * 8;
    const unsigned short* vp0 = vh + (size_t)(wid * 16 + rl) * TT + cc * 8;
    const unsigned short* vp1 = vh + (size_t)(wid * 16 + 8 + rl) * TT + cc * 8;
    const int ldsK0 = wid * 16 * 64, ldsK1 = (wid * 16 + 8) * 64;

    // prologue: stage tile 0 into buffer 0; bump to tile 1
    async16(kp0, &Ks[0][ldsK0]);  async16(kp1, &Ks[0][ldsK1]);
    async16(vp0, &Vs[0][ldsK0]);  async16(vp1, &Vs[0][ldsK1]);
    kp0 += 64 * HD; kp1 += 64 * HD; vp0 += 64; vp1 += 64;

    const int p0s = quad ^ (l16 & 7);
    const int p1s = (4 + quad) ^ (l16 & 7);

#define ATT_STEP(CUR, TT_)                                                              \
    {                                                                                   \
        __syncthreads();                                                                \
        if ((TT_) + 1 < ntiles) {                                                       \
            async16(kp0, &Ks[(CUR) ^ 1][ldsK0]);  async16(kp1, &Ks[(CUR) ^ 1][ldsK1]);  \
            async16(vp0, &Vs[(CUR) ^ 1][ldsK0]);  async16(vp1, &Vs[(CUR) ^ 1][ldsK1]);  \
            kp0 += 64 * HD; kp1 += 64 * HD; vp0 += 64; vp1 += 64;                       \
        }                                                                               \
        const int tk0 = (TT_) * 64;                                                     \
        if (tk0 <= q0w + 31) {                                                          \
            const unsigned short* Kc = Ks[CUR];                                         \
            const unsigned short* Vc = Vs[CUR];                                         \
            s16x8 kf[4][2], vf[4][2];                                                   \
            _Pragma("unroll")                                                           \
            for (int nj = 0; nj < 4; nj++) {                                            \
                kf[nj][0] = *(const s16x8*)&Kc[(nj * 16 + l16) * 64 + p0s * 8];         \
                kf[nj][1] = *(const s16x8*)&Kc[(nj * 16 + l16) * 64 + p1s * 8];         \
            }                                                                           \
            _Pragma("unroll")                                                           \
            for (int ni = 0; ni < 4; ni++) {                                            \
                vf[ni][0] = *(const s16x8*)&Vc[(ni * 16 + l16) * 64 + p0s * 8];         \
                vf[ni][1] = *(const s16x8*)&Vc[(ni * 16 + l16) * 64 + p1s * 8];         \
            }                                                                           \
            _Pragma("unroll")                                                           \
            for (int mf = 0; mf < 2; mf++) {                                            \
                const int f0 = q0w + mf * 16;                                           \
                if (tk0 > f0 + 15) continue;                                            \
                unsigned short* pm = ps + mf * (16 * PST);                              \
                const int qg = f0 + l16;                                                \
                f32x4 st[4];                                                            \
                _Pragma("unroll")                                                       \
                for (int nj = 0; nj < 4; nj++) {                                        \
                    f32x4 z = {};                                                       \
                    z = __builtin_amdgcn_mfma_f32_16x16x32_bf16(kf[nj][0], aq[mf][0], z, 0, 0, 0); \
                    z = __builtin_amdgcn_mfma_f32_16x16x32_bf16(kf[nj][1], aq[mf][1], z, 0, 0, 0); \
                    st[nj] = z;                                                         \
                }                                                                       \
                const bool diag = (tk0 + 64 > f0);                                      \
                _Pragma("unroll")                                                       \
                for (int nj = 0; nj < 4; nj++) {                                        \
                    const int keyb = tk0 + nj * 16 + quad * 4;                          \
                    float pv[4];                                                        \
                    _Pragma("unroll")                                                   \
                    for (int r = 0; r < 4; r++) {                                       \
                        float p = exp2f(st[nj][r]);                                     \
                        if (diag && (keyb + r > qg)) p = 0.f;                           \
                        pv[r] = p;                                                      \
                    }                                                                   \
                    const unsigned int pk0 = __builtin_amdgcn_perm(                     \
                        __float_as_uint(pv[1]), __float_as_uint(pv[0]), 0x07060302u);   \
                    const unsigned int pk1 = __builtin_amdgcn_perm(                     \
                        __float_as_uint(pv[3]), __float_as_uint(pv[2]), 0x07060302u);   \
                    *(uint2*)&pm[l16 * PST + nj * 16 + quad * 4] = make_uint2(pk0, pk1);\
                }                                                                       \
                __asm volatile("s_waitcnt lgkmcnt(0)" ::: "memory");                    \
                const s16x8 ap0 = *(const s16x8*)&pm[l16 * PST + quad * 8];             \
                const s16x8 ap1 = *(const s16x8*)&pm[l16 * PST + 32 + quad * 8];        \
                lacc[mf] = __builtin_amdgcn_mfma_f32_16x16x32_bf16(ap0, onesf, lacc[mf], 0, 0, 0); \
                lacc[mf] = __builtin_amdgcn_mfma_f32_16x16x32_bf16(ap1, onesf, lacc[mf], 0, 0, 0); \
                _Pragma("unroll")                                                       \
                for (int ni = 0; ni < 4; ni++) {                                        \
                    yacc[mf][ni] = __builtin_amdgcn_mfma_f32_16x16x32_bf16(ap0, vf[ni][0], yacc[mf][ni], 0, 0, 0); \
                    yacc[mf][ni] = __builtin_amdgcn_mfma_f32_16x16x32_bf16(ap1, vf[ni][1], yacc[mf][ni], 0, 0, 0); \
                }                                                                       \
            }                                                                           \
        }                                                                               \
    }

    for (int t = 0; t < ntiles; t += 2) {
        ATT_STEP(0, t);
        ATT_STEP(1, t + 1);
    }
#undef ATT_STEP

    // epilogue: lacc[mf][r] is the denominator for q = f0 + quad*4 + r
    const int bbi = bh >> 4, hh = bh & 15;
    #pragma unroll
    for (int mf = 0; mf < 2; mf++) {
        float linv[4];
        #pragma unroll
        for (int r = 0; r < 4; r++)
            linv[r] = 1.0f / lacc[mf][r];
        #pragma unroll
        for (int ni = 0; ni < 4; ni++)
            #pragma unroll
            for (int r = 0; r < 4; r++) {
                const int trow = q0w + mf * 16 + quad * 4 + r;
                yb[((size_t)bbi * TT + trow) * NE + hh * HD + ni * 16 + l16] =
                    f2bf(yacc[mf][ni][r] * linv[r]);
            }
    }
}

extern "C" void kernel_launch(void* const* d_in, const int* in_sizes, int n_in,
                              void* d_out, int out_size, void* d_ws, size_t ws_size,
                              hipStream_t stream) {
    const float* x      = (const float*)d_in[0];
    const float* ln_w   = (const float*)d_in[1];
    const float* ln_b   = (const float*)d_in[2];
    const float* W_attn = (const float*)d_in[3];
    const float* b_attn = (const float*)d_in[4];
    const float* W_proj = (const float*)d_in[5];
    const float* b_proj = (const float*)d_in[6];
    float* out = (float*)d_out;

    char* ws = (char*)d_ws;
    unsigned short* h    = (unsigned short*)ws;  ws += (size_t)MM * C_IN * 2;
    unsigned short* Wat  = (unsigned short*)ws;  ws += (size_t)N_QKV * C_IN * 2;
    unsigned short* Wpt  = (unsigned short*)ws;  ws += (size_t)NE * NE * 2;
    unsigned short* qbuf = (unsigned short*)ws;  ws += (size_t)MM * NE * 2;
    unsigned short* kbuf = (unsigned short*)ws;  ws += (size_t)MM * NE * 2;
    unsigned short* vtbf = (unsigned short*)ws;  ws += (size_t)MM * NE * 2;
    unsigned short* ybuf = (unsigned short*)ws;  ws += (size_t)MM * NE * 2;

    ln_kernel<<<MM, 256, 0, stream>>>(x, ln_w, ln_b, h);
    transpose_cast<<<dim3(N_QKV / 32, C_IN / 32), 256, 0, stream>>>(W_attn, Wat, C_IN, N_QKV);
    transpose_cast<<<dim3(NE / 32, NE / 32), 256, 0, stream>>>(W_proj, Wpt, NE, NE);
    gemm_fm<0><<<dim3(N_QKV / 256, MM / 256), 512, 0, stream>>>(h, Wat, b_attn, qbuf, kbuf, vtbf,
                                                                MM, N_QKV, C_IN);
    attn_kernel<<<64 * 16, 256, 0, stream>>>(qbuf, kbuf, vtbf, ybuf);
    gemm_fm<1><<<dim3(NE / 128, MM / 256), 512, 0, stream>>>(ybuf, Wpt, b_proj, out, nullptr, nullptr,
                                                             MM, NE, NE);
}

// Round 3
// 310.630 us; speedup vs baseline: 1.2091x; 1.1873x over previous
//
#include <hip/hip_runtime.h>
#include <hip/hip_bf16.h>

// ---- constants for this problem ----
#define BB 4
#define TT 2048
#define C_IN 1152
#define NE 1024
#define NH 16
#define HD 64
#define MM (BB*TT)          // 8192
#define N_QKV (3*NE)        // 3072

typedef __attribute__((ext_vector_type(8))) short s16x8;
typedef __attribute__((ext_vector_type(4))) float f32x4;

static __device__ __forceinline__ unsigned short f2bf(float x) {
    unsigned int u = __float_as_uint(x);
    unsigned int r = (u + 0x7fffu + ((u >> 16) & 1u)) >> 16;
    return (unsigned short)r;
}

// async global->LDS, 16 B per lane. LDS dest = wave-uniform base + lane*16.
static __device__ __forceinline__ void async16(const void* g, void* l) {
    __builtin_amdgcn_global_load_lds((const __attribute__((address_space(1))) void*)g,
                                     (__attribute__((address_space(3))) void*)l, 16, 0, 0);
}

// ---------------- LayerNorm: x fp32 [M][C_IN] -> h bf16 [M][C_IN] ----------------
__global__ __launch_bounds__(256) void ln_kernel(const float* __restrict__ x,
                                                 const float* __restrict__ w,
                                                 const float* __restrict__ b,
                                                 unsigned short* __restrict__ h) {
    const int row = blockIdx.x;
    const float* xr = x + (size_t)row * C_IN;
    float s = 0.f, sq = 0.f;
    for (int i = threadIdx.x; i < C_IN; i += 256) {
        float v = xr[i];
        s += v; sq += v * v;
    }
    for (int off = 1; off < 64; off <<= 1) {
        s  += __shfl_xor(s, off, 64);
        sq += __shfl_xor(sq, off, 64);
    }
    __shared__ float red[2][4];
    const int wid = threadIdx.x >> 6, lane = threadIdx.x & 63;
    if (lane == 0) { red[0][wid] = s; red[1][wid] = sq; }
    __syncthreads();
    s  = red[0][0] + red[0][1] + red[0][2] + red[0][3];
    sq = red[1][0] + red[1][1] + red[1][2] + red[1][3];
    const float mu  = s * (1.f / C_IN);
    const float var = sq * (1.f / C_IN) - mu * mu;
    const float rs  = rsqrtf(var + 1e-5f);
    unsigned short* hr = h + (size_t)row * C_IN;
    for (int i = threadIdx.x; i < C_IN; i += 256) {
        float v = (xr[i] - mu) * rs * w[i] + b[i];
        hr[i] = f2bf(v);
    }
}

// ------------- transpose+cast: in fp32 [K][N] -> out bf16 [N][K] -------------
__global__ __launch_bounds__(256) void transpose_cast(const float* __restrict__ in,
                                                      unsigned short* __restrict__ out,
                                                      int K, int N) {
    __shared__ float tile[32][33];
    const int n0 = blockIdx.x * 32, k0 = blockIdx.y * 32;
    const int tx = threadIdx.x & 31, ty = threadIdx.x >> 5;   // 32 x 8
    for (int i = ty; i < 32; i += 8)
        tile[i][tx] = in[(size_t)(k0 + i) * N + n0 + tx];
    __syncthreads();
    for (int i = ty; i < 32; i += 8)
        out[(size_t)(n0 + i) * K + k0 + tx] = f2bf(tile[tx][i]);
}

#define ATT_SC 0.18033688011112042f   /* (1/8) * log2(e) */

// ------------- GEMM: A bf16 [M][K] x Bt bf16 [N][K] + bias -> epilogue -------------
// Round-0 proven 128x128 structure (4 waves, double-buffered global_load_lds,
// one barrier per k-tile) + bijective XCD-chunked blockIdx swizzle (T1).
// MODE 0: QKV with LDS-routed coalesced epilogue; q PRE-SCALED by ATT_SC.
// MODE 1: plain fp32 out [M][N] direct stores.
#define EP_STRIDE 136   /* ushort; 272 B rows keep 16 B alignment for b128 */
template <int MODE>
__global__ __launch_bounds__(256) void gemm_bt(const unsigned short* __restrict__ A,
                                               const unsigned short* __restrict__ Bt,
                                               const float* __restrict__ bias,
                                               void* __restrict__ outp,
                                               unsigned short* __restrict__ kb,
                                               unsigned short* __restrict__ vt,
                                               int M, int N, int K) {
    __shared__ unsigned short smem[16384];          // 32 KB
    unsigned short* As = smem;                      // [2][128*32]
    unsigned short* Bs = smem + 8192;
    const int tid = threadIdx.x;
    const int wid = tid >> 6, lane = tid & 63;
    const int wm = wid >> 1, wn = wid & 1;
    const int quad = lane >> 4, l16 = lane & 15;

    // T1: bijective XCD-chunked swizzle (nwg % 8 == 0 for both grids)
    const int gx  = gridDim.x;
    const int nwg = gx * gridDim.y;
    const int bid = blockIdx.y * gx + blockIdx.x;
    const int wg  = (bid & 7) * (nwg >> 3) + (bid >> 3);
    const int m0 = (wg / gx) * 128, n0 = (wg % gx) * 128;

    const int srow = wid * 32 + (lane >> 2);     // + {0,16}
    const int scol = (lane & 3) * 8;
    const unsigned short* gA = A  + (size_t)(m0 + srow) * K + scol;
    const unsigned short* gB = Bt + (size_t)(n0 + srow) * K + scol;
    const int lofs = (wid * 32) * 32;

    f32x4 acc[4][4] = {};

    async16(gA,          &As[lofs]);
    async16(gA + 16 * K, &As[lofs + 16 * 32]);
    async16(gB,          &Bs[lofs]);
    async16(gB + 16 * K, &Bs[lofs + 16 * 32]);

    const int nk = K >> 5;
    for (int kt = 0; kt < nk; kt++) {
        __syncthreads();
        const int cur = kt & 1;
        if (kt + 1 < nk) {
            const int kk = (kt + 1) << 5;
            const int nxt = (cur ^ 1) * 4096;
            async16(gA + kk,          &As[nxt + lofs]);
            async16(gA + kk + 16 * K, &As[nxt + lofs + 16 * 32]);
            async16(gB + kk,          &Bs[nxt + lofs]);
            async16(gB + kk + 16 * K, &Bs[nxt + lofs + 16 * 32]);
        }
        const int cb = cur * 4096;
        s16x8 af[4], bfb[4];
        for (int mi = 0; mi < 4; mi++)
            af[mi] = *(const s16x8*)&As[cb + (wm * 64 + mi * 16 + l16) * 32 + quad * 8];
        for (int ni = 0; ni < 4; ni++)
            bfb[ni] = *(const s16x8*)&Bs[cb + (wn * 64 + ni * 16 + l16) * 32 + quad * 8];
        for (int mi = 0; mi < 4; mi++)
            for (int ni = 0; ni < 4; ni++)
                acc[mi][ni] = __builtin_amdgcn_mfma_f32_16x16x32_bf16(af[mi], bfb[ni], acc[mi][ni], 0, 0, 0);
    }

    // bias into registers (+ ATT_SC pre-scale for the q third)
    const int which0 = n0 >> 10;
    const float sc = (MODE == 0 && which0 == 0) ? ATT_SC : 1.0f;
    for (int ni = 0; ni < 4; ni++) {
        const float bv = bias[n0 + wn * 64 + ni * 16 + l16];
        for (int mi = 0; mi < 4; mi++)
            for (int r = 0; r < 4; r++)
                acc[mi][ni][r] = (acc[mi][ni][r] + bv) * sc;
    }

    if (MODE == 1) {
        for (int mi = 0; mi < 4; mi++) {
            const int mbase = m0 + wm * 64 + mi * 16 + quad * 4;
            for (int ni = 0; ni < 4; ni++) {
                const int n_g = n0 + wn * 64 + ni * 16 + l16;
                for (int r = 0; r < 4; r++)
                    ((float*)outp)[(size_t)(mbase + r) * N + n_g] = acc[mi][ni][r];
            }
        }
        return;
    }

    // ---- MODE 0: LDS-routed coalesced epilogue ----
    const int which = n0 >> 10;                    // 0=q 1=k 2=v (uniform)
    const int bb = m0 >> 11;
    const int mloc = m0 & 2047;                    // batch-local time base
    unsigned short* T = smem;                      // [64][EP_STRIDE]

    if (which < 2) {
        // row layout [m_local 64][n_local 128]; two m-half passes
        unsigned short* qk = (which == 0) ? (unsigned short*)outp : kb;
        for (int pass = 0; pass < 2; pass++) {
            __syncthreads();
            if (wm == pass) {
                for (int mi = 0; mi < 4; mi++)
                    for (int ni = 0; ni < 4; ni++) {
                        const int nl = wn * 64 + ni * 16 + l16;
                        for (int r = 0; r < 4; r++)
                            T[(mi * 16 + quad * 4 + r) * EP_STRIDE + nl] = f2bf(acc[mi][ni][r]);
                    }
            }
            __syncthreads();
            const int ml = tid >> 2, c = tid & 3;
            const int t  = mloc + pass * 64 + ml;
            const int nl0 = c * 32;
            const int hh = ((n0 & 1023) >> 6) + (nl0 >> 6);
            const int d0 = nl0 & 63;
            unsigned short* dst = qk + ((size_t)(bb * 16 + hh) * TT + t) * HD + d0;
            const unsigned short* src = &T[ml * EP_STRIDE + nl0];
            for (int u = 0; u < 4; u++)
                *(s16x8*)(dst + u * 8) = *(const s16x8*)(src + u * 8);
        }
    } else {
        // transposed layout [n_local 64][m_local 128]; two n-half passes
        for (int pass = 0; pass < 2; pass++) {
            __syncthreads();
            if (wn == pass) {
                for (int mi = 0; mi < 4; mi++)
                    for (int ni = 0; ni < 4; ni++) {
                        const int nlh = ni * 16 + l16;
                        const int mlb = wm * 64 + mi * 16 + quad * 4;
                        for (int r = 0; r < 4; r += 2) {
                            const unsigned int pk = (unsigned int)f2bf(acc[mi][ni][r]) |
                                                    ((unsigned int)f2bf(acc[mi][ni][r + 1]) << 16);
                            *(unsigned int*)&T[nlh * EP_STRIDE + mlb + r] = pk;
                        }
                    }
            }
            __syncthreads();
            const int nlh = tid >> 2, c = tid & 3;
            const int hh = (n0 - 2048 + pass * 64) >> 6;
            unsigned short* dst = vt + ((size_t)(bb * 16 + hh) * HD + nlh) * TT + mloc + c * 32;
            const unsigned short* src = &T[nlh * EP_STRIDE + c * 32];
            for (int u = 0; u < 4; u++)
                *(s16x8*)(dst + u * 8) = *(const s16x8*)(src + u * 8);
        }
    }
}

// ------------- flash attention: S^T trick + ones-MFMA row sums -------------
// q (pre-scaled by ATT_SC), k [BH][T][64] bf16, vt [BH][64][T] bf16 -> y bf16 [B][T][NE]
//
// Round-3 changes:
// - 3-buffer K/V staging + raw s_barrier + COUNTED vmcnt(4): stage(t+2) issued at
//   step t stays in flight across barrier t+1 (true prefetch pipelining; the old
//   __syncthreads drained vmcnt(0) every step). Safety: buffer (t+2)%3 == (t-1)%3;
//   its readers (step t-1) all precede barrier t, the writes all follow it.
// - Both mf-halves merged: one QK/exp/pack phase, ONE lgkmcnt(0) fence (was 2),
//   then one 24-MFMA rowsum+PV cluster wrapped in setprio(1) (T5, m191).
#define PST 72                         /* shorts; 144 B rows, 16B-aligned */

__global__ __launch_bounds__(256) void attn_kernel(const unsigned short* __restrict__ qb,
                                                   const unsigned short* __restrict__ kb,
                                                   const unsigned short* __restrict__ vt,
                                                   unsigned short* __restrict__ yb) {
    __shared__ unsigned short Ks[3][64 * 64];
    __shared__ unsigned short Vs[3][64 * 64];
    __shared__ unsigned short Ps[4][2 * 16 * PST];   // per-wave, per-mf [16 q][PST]
    const int tid = threadIdx.x, wid = tid >> 6, lane = tid & 63;
    const int quad = lane >> 4, l16 = lane & 15;
    const int bh = blockIdx.x & 63;
    const int qblk = 15 - (blockIdx.x >> 6);         // longest-first (LPT packing)

    const unsigned short* qh = qb + (size_t)bh * TT * HD;
    const unsigned short* kh = kb + (size_t)bh * TT * HD;
    const unsigned short* vh = vt + (size_t)bh * HD * TT;
    unsigned short* ps = Ps[wid];

    const int q0w = qblk * 128 + wid * 32;           // this wave's 32 q-rows
    s16x8 aq[2][2];
    #pragma unroll
    for (int mf = 0; mf < 2; mf++) {
        aq[mf][0] = *(const s16x8*)&qh[(size_t)(q0w + mf * 16 + l16) * HD + quad * 8];
        aq[mf][1] = *(const s16x8*)&qh[(size_t)(q0w + mf * 16 + l16) * HD + 32 + quad * 8];
    }
    // ones B-frag (bf16 1.0 = 0x3F80)
    s16x8 onesf;
    #pragma unroll
    for (int i = 0; i < 8; i++) onesf[i] = (short)0x3F80;

    f32x4 yacc[2][4] = {};
    f32x4 lacc[2] = {};                              // row-sum accumulators
    const int ntiles = 2 * qblk + 2;                 // always even, >= 2

    // staging: row r = wid*16 + {0,8} + rl, chunk cc XOR-swizzled; pointers bumped
    const int rl = lane >> 3;
    const int cc = (lane & 7) ^ (rl & 7);
    const unsigned short* kp0 = kh + (size_t)(wid * 16 + rl) * HD + cc * 8;
    const unsigned short* kp1 = kh + (size_t)(wid * 16 + 8 + rl) * HD + cc * 8;
    const unsigned short* vp0 = vh + (size_t)(wid * 16 + rl) * TT + cc * 8;
    const unsigned short* vp1 = vh + (size_t)(wid * 16 + 8 + rl) * TT + cc * 8;
    const int ldsK0 = wid * 16 * 64, ldsK1 = (wid * 16 + 8) * 64;

    // prologue: stage tiles 0 and 1
    async16(kp0, &Ks[0][ldsK0]);  async16(kp1, &Ks[0][ldsK1]);
    async16(vp0, &Vs[0][ldsK0]);  async16(vp1, &Vs[0][ldsK1]);
    kp0 += 64 * HD; kp1 += 64 * HD; vp0 += 64; vp1 += 64;
    async16(kp0, &Ks[1][ldsK0]);  async16(kp1, &Ks[1][ldsK1]);
    async16(vp0, &Vs[1][ldsK0]);  async16(vp1, &Vs[1][ldsK1]);
    kp0 += 64 * HD; kp1 += 64 * HD; vp0 += 64; vp1 += 64;

    const int p0s = quad ^ (l16 & 7);
    const int p1s = (4 + quad) ^ (l16 & 7);

    int bsel = 0;
    for (int t = 0; t < ntiles; ++t) {
        // counted wait: stage(t) done; stage(t+1) (4 loads) may stay in flight
        if (t + 1 < ntiles) { asm volatile("s_waitcnt vmcnt(4)" ::: "memory"); }
        else                { asm volatile("s_waitcnt vmcnt(0)" ::: "memory"); }
        __builtin_amdgcn_s_barrier();
        if (t + 2 < ntiles) {
            const int wsel = (bsel == 0) ? 2 : bsel - 1;   // (bsel+2)%3
            async16(kp0, &Ks[wsel][ldsK0]);  async16(kp1, &Ks[wsel][ldsK1]);
            async16(vp0, &Vs[wsel][ldsK0]);  async16(vp1, &Vs[wsel][ldsK1]);
            kp0 += 64 * HD; kp1 += 64 * HD; vp0 += 64; vp1 += 64;
        }
        const int tk0 = t * 64;
        if (tk0 <= q0w + 31) {
            const unsigned short* Kc = Ks[bsel];
            const unsigned short* Vc = Vs[bsel];
            s16x8 kf[4][2], vf[4][2];
            #pragma unroll
            for (int nj = 0; nj < 4; nj++) {
                kf[nj][0] = *(const s16x8*)&Kc[(nj * 16 + l16) * 64 + p0s * 8];
                kf[nj][1] = *(const s16x8*)&Kc[(nj * 16 + l16) * 64 + p1s * 8];
            }
            #pragma unroll
            for (int ni = 0; ni < 4; ni++) {
                vf[ni][0] = *(const s16x8*)&Vc[(ni * 16 + l16) * 64 + p0s * 8];
                vf[ni][1] = *(const s16x8*)&Vc[(ni * 16 + l16) * 64 + p1s * 8];
            }
            // ---- QK + exp + pack + P-store, both mf halves ----
            #pragma unroll
            for (int mf = 0; mf < 2; mf++) {
                const int f0 = q0w + mf * 16;
                unsigned short* pm = ps + mf * (16 * PST);
                const int qg = f0 + l16;
                f32x4 st[4];
                #pragma unroll
                for (int nj = 0; nj < 4; nj++) {
                    f32x4 z = {};
                    z = __builtin_amdgcn_mfma_f32_16x16x32_bf16(kf[nj][0], aq[mf][0], z, 0, 0, 0);
                    z = __builtin_amdgcn_mfma_f32_16x16x32_bf16(kf[nj][1], aq[mf][1], z, 0, 0, 0);
                    st[nj] = z;
                }
                const bool diag = (tk0 + 64 > f0);
                #pragma unroll
                for (int nj = 0; nj < 4; nj++) {
                    const int keyb = tk0 + nj * 16 + quad * 4;
                    float pv[4];
                    #pragma unroll
                    for (int r = 0; r < 4; r++) {
                        float p = exp2f(st[nj][r]);
                        if (diag && (keyb + r > qg)) p = 0.f;
                        pv[r] = p;
                    }
                    const unsigned int pk0 = __builtin_amdgcn_perm(
                        __float_as_uint(pv[1]), __float_as_uint(pv[0]), 0x07060302u);
                    const unsigned int pk1 = __builtin_amdgcn_perm(
                        __float_as_uint(pv[3]), __float_as_uint(pv[2]), 0x07060302u);
                    *(uint2*)&pm[l16 * PST + nj * 16 + quad * 4] = make_uint2(pk0, pk1);
                }
            }
            // ---- single fence, then rowsum + PV cluster (T5) ----
            __asm volatile("s_waitcnt lgkmcnt(0)" ::: "memory");
            __builtin_amdgcn_s_setprio(1);
            #pragma unroll
            for (int mf = 0; mf < 2; mf++) {
                unsigned short* pm = ps + mf * (16 * PST);
                const s16x8 ap0 = *(const s16x8*)&pm[l16 * PST + quad * 8];
                const s16x8 ap1 = *(const s16x8*)&pm[l16 * PST + 32 + quad * 8];
                lacc[mf] = __builtin_amdgcn_mfma_f32_16x16x32_bf16(ap0, onesf, lacc[mf], 0, 0, 0);
                lacc[mf] = __builtin_amdgcn_mfma_f32_16x16x32_bf16(ap1, onesf, lacc[mf], 0, 0, 0);
                #pragma unroll
                for (int ni = 0; ni < 4; ni++) {
                    yacc[mf][ni] = __builtin_amdgcn_mfma_f32_16x16x32_bf16(ap0, vf[ni][0], yacc[mf][ni], 0, 0, 0);
                    yacc[mf][ni] = __builtin_amdgcn_mfma_f32_16x16x32_bf16(ap1, vf[ni][1], yacc[mf][ni], 0, 0, 0);
                }
            }
            __builtin_amdgcn_s_setprio(0);
        }
        bsel = (bsel == 2) ? 0 : bsel + 1;
    }

    // epilogue: lacc[mf][r] is the denominator for q = f0 + quad*4 + r — the exact
    // same (quad,r) indexing as yacc. No cross-lane reduction needed.
    const int bbi = bh >> 4, hh = bh & 15;
    #pragma unroll
    for (int mf = 0; mf < 2; mf++) {
        float linv[4];
        #pragma unroll
        for (int r = 0; r < 4; r++)
            linv[r] = 1.0f / lacc[mf][r];
        #pragma unroll
        for (int ni = 0; ni < 4; ni++)
            #pragma unroll
            for (int r = 0; r < 4; r++) {
                const int trow = q0w + mf * 16 + quad * 4 + r;
                yb[((size_t)bbi * TT + trow) * NE + hh * HD + ni * 16 + l16] =
                    f2bf(yacc[mf][ni][r] * linv[r]);
            }
    }
}

extern "C" void kernel_launch(void* const* d_in, const int* in_sizes, int n_in,
                              void* d_out, int out_size, void* d_ws, size_t ws_size,
                              hipStream_t stream) {
    const float* x      = (const float*)d_in[0];
    const float* ln_w   = (const float*)d_in[1];
    const float* ln_b   = (const float*)d_in[2];
    const float* W_attn = (const float*)d_in[3];
    const float* b_attn = (const float*)d_in[4];
    const float* W_proj = (const float*)d_in[5];
    const float* b_proj = (const float*)d_in[6];
    float* out = (float*)d_out;

    char* ws = (char*)d_ws;
    unsigned short* h    = (unsigned short*)ws;  ws += (size_t)MM * C_IN * 2;
    unsigned short* Wat  = (unsigned short*)ws;  ws += (size_t)N_QKV * C_IN * 2;
    unsigned short* Wpt  = (unsigned short*)ws;  ws += (size_t)NE * NE * 2;
    unsigned short* qbuf = (unsigned short*)ws;  ws += (size_t)MM * NE * 2;
    unsigned short* kbuf = (unsigned short*)ws;  ws += (size_t)MM * NE * 2;
    unsigned short* vtbf = (unsigned short*)ws;  ws += (size_t)MM * NE * 2;
    unsigned short* ybuf = (unsigned short*)ws;  ws += (size_t)MM * NE * 2;

    ln_kernel<<<MM, 256, 0, stream>>>(x, ln_w, ln_b, h);
    transpose_cast<<<dim3(N_QKV / 32, C_IN / 32), 256, 0, stream>>>(W_attn, Wat, C_IN, N_QKV);
    transpose_cast<<<dim3(NE / 32, NE / 32), 256, 0, stream>>>(W_proj, Wpt, NE, NE);
    gemm_bt<0><<<dim3(N_QKV / 128, MM / 128), 256, 0, stream>>>(h, Wat, b_attn, qbuf, kbuf, vtbf,
                                                                MM, N_QKV, C_IN);
    attn_kernel<<<64 * 16, 256, 0, stream>>>(qbuf, kbuf, vtbf, ybuf);
    gemm_bt<1><<<dim3(NE / 128, MM / 128), 256, 0, stream>>>(ybuf, Wpt, b_proj, out, nullptr, nullptr,
                                                             MM, NE, NE);
}